// Round 1
// baseline (379.003 us; speedup 1.0000x reference)
//
#include <hip/hip_runtime.h>

typedef unsigned short u16;
typedef unsigned int   u32;
typedef __bf16  bf16x8 __attribute__((ext_vector_type(8)));
typedef u16     u16x8  __attribute__((ext_vector_type(8)));
typedef float   f32x4  __attribute__((ext_vector_type(4)));

#define S_LEN   4096
#define DMODEL  512
#define NBATCH  4
#define NTILE   32          // S/128
#define NPAIR   528         // NTILE*(NTILE+1)/2

__device__ __forceinline__ u16 f2bf(float x){
  u32 u = __float_as_uint(x);
  return (u16)((u + 0x7fffu + ((u >> 16) & 1u)) >> 16);   // RNE
}
__device__ __forceinline__ float bf2f(u16 u){ return __uint_as_float(((u32)u) << 16); }

__device__ __forceinline__ void gload_lds16(const void* g, void* l){
  __builtin_amdgcn_global_load_lds((const __attribute__((address_space(1))) void*)g,
                                   (__attribute__((address_space(3))) void*)l, 16, 0, 0);
}

__device__ __forceinline__ bf16x8 ones_frag(){
  u16x8 u = {0x3F80,0x3F80,0x3F80,0x3F80,0x3F80,0x3F80,0x3F80,0x3F80}; // bf16 1.0
  return __builtin_bit_cast(bf16x8, u);
}

// ---------------- cast f32 -> bf16, 8 elems/thread ----------------
__global__ __launch_bounds__(256) void cast_kernel(const float* __restrict__ in,
                                                   u16* __restrict__ out, int n8){
  int i = blockIdx.x * 256 + threadIdx.x;
  int stride = gridDim.x * 256;
  for (; i < n8; i += stride){
    const float4* p = (const float4*)in + (size_t)i * 2;
    float4 a = p[0], b = p[1];
    ushort4 o0 = make_ushort4(f2bf(a.x), f2bf(a.y), f2bf(a.z), f2bf(a.w));
    ushort4 o1 = make_ushort4(f2bf(b.x), f2bf(b.y), f2bf(b.z), f2bf(b.w));
    ((ushort4*)out)[(size_t)i*2]   = o0;
    ((ushort4*)out)[(size_t)i*2+1] = o1;
  }
}

// ---------------- one BK=32 K-step of a 128x128 NT GEMM -----------
// A,B point at (row0, k0) of row-major bf16 matrices with leading dims lda/ldb.
// LDS tiles are linear [128][32]. 4 waves, wave (wr,wc) owns a 64x64 sub-tile.
template<bool ZS>
__device__ __forceinline__ void mma_step(const u16* __restrict__ A, int lda,
                                         const u16* __restrict__ B, int ldb,
                                         u16* ldsA, u16* ldsB,
                                         f32x4 acc[4][4], f32x4* accz, bf16x8 ones,
                                         int w, int l, int wr, int wc)
{
  int srow = l >> 2, scol = (l & 3) * 8;
  #pragma unroll
  for (int cc = 0; cc < 2; ++cc){
    int c = w + cc * 4;                       // chunk = 16 rows = 1KB per wave issue
    gload_lds16(A + (size_t)(c*16 + srow)*lda + scol, ldsA + c*512);
    gload_lds16(B + (size_t)(c*16 + srow)*ldb + scol, ldsB + c*512);
  }
  __syncthreads();                            // drains vmcnt before use
  int lo = l & 15, hi = l >> 4;
  bf16x8 a[4], b[4];
  #pragma unroll
  for (int m = 0; m < 4; m++) a[m] = *(const bf16x8*)(ldsA + (wr*64 + m*16 + lo)*32 + hi*8);
  #pragma unroll
  for (int n = 0; n < 4; n++) b[n] = *(const bf16x8*)(ldsB + (wc*64 + n*16 + lo)*32 + hi*8);
  #pragma unroll
  for (int m = 0; m < 4; m++){
    if constexpr (ZS)
      accz[m] = __builtin_amdgcn_mfma_f32_16x16x32_bf16(a[m], ones, accz[m], 0, 0, 0);
    #pragma unroll
    for (int n = 0; n < 4; n++)
      acc[m][n] = __builtin_amdgcn_mfma_f32_16x16x32_bf16(a[m], b[n], acc[m][n], 0, 0, 0);
  }
  __syncthreads();                            // protect LDS before next stage
}

// ---------------- projection: Y = X * W^T + bias, bf16 out --------
__global__ __launch_bounds__(256) void proj_kernel(const u16* __restrict__ X,
                                                   const u16* __restrict__ W,
                                                   const float* __restrict__ bias,
                                                   u16* __restrict__ Y)
{
  __shared__ __align__(16) u16 ldsA[4096], ldsB[4096];
  int cn = blockIdx.x, rm = blockIdx.y;
  int t = threadIdx.x, w = t >> 6, l = t & 63, wr = w >> 1, wc = w & 1;
  f32x4 zero = {0.f,0.f,0.f,0.f};
  f32x4 acc[4][4];
  #pragma unroll
  for (int m = 0; m < 4; m++)
    #pragma unroll
    for (int n = 0; n < 4; n++) acc[m][n] = zero;

  const u16* A = X + (size_t)rm * 128 * DMODEL;
  const u16* B = W + (size_t)cn * 128 * DMODEL;
  for (int s = 0; s < 16; s++)
    mma_step<false>(A + s*32, DMODEL, B + s*32, DMODEL, ldsA, ldsB, acc, nullptr,
                    ones_frag(), w, l, wr, wc);

  int lo = l & 15, hi = l >> 4;
  #pragma unroll
  for (int n = 0; n < 4; n++){
    int col = cn*128 + wc*64 + n*16 + lo;
    float bs = bias[col];
    #pragma unroll
    for (int m = 0; m < 4; m++){
      int row0 = rm*128 + wr*64 + m*16 + hi*4;
      #pragma unroll
      for (int j = 0; j < 4; j++)
        Y[(size_t)(row0 + j) * DMODEL + col] = f2bf(acc[m][n][j] + bs);
    }
  }
}

// ---------------- V transpose: Vt[b][c][k] = V[b][k][c] -----------
__global__ __launch_bounds__(256) void transpose_kernel(const u16* __restrict__ V,
                                                        u16* __restrict__ Vt)
{
  __shared__ u16 tile[64][66];
  int k0 = blockIdx.x * 64, c0 = blockIdx.y * 64, b = blockIdx.z;
  int t = threadIdx.x;
  #pragma unroll
  for (int i = 0; i < 16; i++){
    int idx = i*256 + t; int r = idx >> 6, c = idx & 63;
    tile[r][c] = V[((size_t)b*S_LEN + k0 + r) * DMODEL + c0 + c];
  }
  __syncthreads();
  #pragma unroll
  for (int i = 0; i < 16; i++){
    int idx = i*256 + t; int r = idx >> 6, c = idx & 63;
    Vt[((size_t)b*DMODEL + c0 + r) * S_LEN + k0 + c] = tile[c][r];
  }
}

// ---------------- V per-tile column sums --------------------------
__global__ __launch_bounds__(256) void vpart_kernel(const u16* __restrict__ V,
                                                    float* __restrict__ part){
  int t = blockIdx.x, b = blockIdx.y, c = threadIdx.x;
  const u16* base = V + ((size_t)b*S_LEN + t*128) * DMODEL;
  float s0 = 0.f, s1 = 0.f;
  for (int k = 0; k < 128; k++){
    s0 += bf2f(base[(size_t)k*DMODEL + c]);
    s1 += bf2f(base[(size_t)k*DMODEL + 256 + c]);
  }
  part[((size_t)b*NTILE + t)*DMODEL + c]       = s0;
  part[((size_t)b*NTILE + t)*DMODEL + 256 + c] = s1;
}

// suffix_coarse[b][t][c] = sum of V rows in tiles > t
__global__ void suffix_kernel(const float* __restrict__ part, float* __restrict__ sufx){
  int b = blockIdx.x, c = threadIdx.x;
  float s = 0.f;
  for (int t = NTILE - 1; t >= 0; t--){
    sufx[((size_t)b*NTILE + t)*DMODEL + c] = s;
    s += part[((size_t)b*NTILE + t)*DMODEL + c];
  }
}

// ---------------- scores: P = exp(mask(Q K^T * scale)) ------------
__global__ __launch_bounds__(256) void score_kernel(const u16* __restrict__ Q,
                                                    const u16* __restrict__ K,
                                                    u16* __restrict__ P)
{
  __shared__ __align__(16) u16 ldsA[4096], ldsB[4096];
  int p = blockIdx.x, b = blockIdx.y;
  int qt = (int)((sqrtf(8.f*p + 1.f) - 1.f) * 0.5f);
  while ((qt+1)*(qt+2)/2 <= p) qt++;
  while (qt*(qt+1)/2 > p) qt--;
  int kt = p - qt*(qt+1)/2;

  int t = threadIdx.x, w = t >> 6, l = t & 63, wr = w >> 1, wc = w & 1;
  f32x4 zero = {0.f,0.f,0.f,0.f};
  f32x4 acc[4][4];
  #pragma unroll
  for (int m = 0; m < 4; m++)
    #pragma unroll
    for (int n = 0; n < 4; n++) acc[m][n] = zero;

  const u16* A = Q + ((size_t)b*S_LEN + qt*128) * DMODEL;
  const u16* B = K + ((size_t)b*S_LEN + kt*128) * DMODEL;
  for (int s = 0; s < 16; s++)
    mma_step<false>(A + s*32, DMODEL, B + s*32, DMODEL, ldsA, ldsB, acc, nullptr,
                    ones_frag(), w, l, wr, wc);

  const float scale = 0.044194173824159216f;   // 1/sqrt(512)
  u16* Pt = P + ((size_t)b*NPAIR + p) * 16384;
  int lo = l & 15, hi = l >> 4;
  bool diag = (qt == kt);
  #pragma unroll
  for (int m = 0; m < 4; m++){
    #pragma unroll
    for (int n = 0; n < 4; n++){
      int cl = wc*64 + n*16 + lo;
      #pragma unroll
      for (int j = 0; j < 4; j++){
        int rl = wr*64 + m*16 + hi*4 + j;
        float s = acc[m][n][j] * scale;
        if (diag && cl > rl) s = 0.f;          // masked: score 0 -> P = 1
        Pt[(size_t)rl*128 + cl] = f2bf(__expf(s));
      }
    }
  }
}

// ---------------- PV: out = (P·V + suffix) / (rowsum(P)+count) ----
__global__ __launch_bounds__(256) void pv_kernel(const u16* __restrict__ P,
                                                 const u16* __restrict__ Vt,
                                                 const float* __restrict__ sufx,
                                                 float* __restrict__ out)
{
  __shared__ __align__(16) u16 ldsA[4096], ldsB[4096];
  int ct = blockIdx.x, qt = (NTILE - 1) - blockIdx.y, b = blockIdx.z; // big tiles first
  int t = threadIdx.x, w = t >> 6, l = t & 63, wr = w >> 1, wc = w & 1;
  f32x4 zero = {0.f,0.f,0.f,0.f};
  f32x4 acc[4][4]; f32x4 accz[4];
  #pragma unroll
  for (int m = 0; m < 4; m++){
    accz[m] = zero;
    #pragma unroll
    for (int n = 0; n < 4; n++) acc[m][n] = zero;
  }
  bf16x8 ones = ones_frag();

  for (int kt = 0; kt <= qt; ++kt){
    const u16* A = P + ((size_t)b*NPAIR + qt*(qt+1)/2 + kt) * 16384;   // P tile [128][128]
    const u16* B = Vt + ((size_t)b*DMODEL + ct*128) * S_LEN + kt*128;  // Vt rows=cols of V
    #pragma unroll 1
    for (int s = 0; s < 4; s++)
      mma_step<true>(A + s*32, 128, B + s*32, S_LEN, ldsA, ldsB, acc, accz,
                     ones, w, l, wr, wc);
  }

  float zadd = (float)(S_LEN - (qt+1)*128);    // future tiles contribute exp(0)=1 each
  int lo = l & 15, hi = l >> 4;
  const float* suf = sufx + ((size_t)b*NTILE + qt)*DMODEL + ct*128;
  #pragma unroll
  for (int m = 0; m < 4; m++){
    #pragma unroll
    for (int j = 0; j < 4; j++){
      float Z = accz[m][j] + zadd;
      int rl = wr*64 + m*16 + hi*4 + j;
      #pragma unroll
      for (int n = 0; n < 4; n++){
        int cl = wc*64 + n*16 + lo;
        float o = (acc[m][n][j] + suf[cl]) / Z;
        out[((size_t)b*S_LEN + qt*128 + rl) * DMODEL + ct*128 + cl] = o;
      }
    }
  }
}

// ------------------------------------------------------------------
extern "C" void kernel_launch(void* const* d_in, const int* in_sizes, int n_in,
                              void* d_out, int out_size, void* d_ws, size_t ws_size,
                              hipStream_t stream)
{
  const float* q_in = (const float*)d_in[0];
  const float* k_in = (const float*)d_in[1];
  const float* v_in = (const float*)d_in[2];
  const float* Wq   = (const float*)d_in[3];
  const float* bq   = (const float*)d_in[4];
  const float* Wk   = (const float*)d_in[5];
  const float* bk   = (const float*)d_in[6];
  const float* Wv   = (const float*)d_in[7];
  const float* bv   = (const float*)d_in[8];
  float* out = (float*)d_out;
  char*  ws  = (char*)d_ws;

  const size_t NTOK  = (size_t)NBATCH * S_LEN;       // 16384
  const size_t TEN_B = NTOK * DMODEL * 2;            // 16.8 MB bf16 tensor

  size_t off = 0;
  u16* Wq_b = (u16*)(ws + off); off += DMODEL*DMODEL*2;
  u16* Wk_b = (u16*)(ws + off); off += DMODEL*DMODEL*2;
  u16* Wv_b = (u16*)(ws + off); off += DMODEL*DMODEL*2;
  // union region: input bf16 casts (used only through projections) / P tiles (after)
  size_t uoff = off;
  u16* qx = (u16*)(ws + uoff);
  u16* kx = qx + NTOK*DMODEL;
  u16* vx = kx + NTOK*DMODEL;
  u16* Pbuf = (u16*)(ws + uoff);
  size_t usize = (size_t)NBATCH * NPAIR * 16384 * 2; // 69.2 MB >= 3 casts
  off = uoff + usize;
  u16* Qb  = (u16*)(ws + off); off += TEN_B;
  u16* Kb  = (u16*)(ws + off); off += TEN_B;
  u16* Vb  = (u16*)(ws + off); off += TEN_B;
  u16* Vtb = (u16*)(ws + off); off += TEN_B;
  float* part = (float*)(ws + off); off += (size_t)NBATCH*NTILE*DMODEL*4;
  float* sufx = (float*)(ws + off); off += (size_t)NBATCH*NTILE*DMODEL*4;
  // total ~138.4 MB of ws

  int n8_big = (int)(NTOK * DMODEL / 8);   // 1048576
  int n8_w   = DMODEL * DMODEL / 8;        // 32768
  cast_kernel<<<2048, 256, 0, stream>>>(q_in, qx, n8_big);
  cast_kernel<<<2048, 256, 0, stream>>>(k_in, kx, n8_big);
  cast_kernel<<<2048, 256, 0, stream>>>(v_in, vx, n8_big);
  cast_kernel<<<128, 256, 0, stream>>>(Wq, Wq_b, n8_w);
  cast_kernel<<<128, 256, 0, stream>>>(Wk, Wk_b, n8_w);
  cast_kernel<<<128, 256, 0, stream>>>(Wv, Wv_b, n8_w);

  dim3 pg(DMODEL/128, (unsigned)(NTOK/128));         // 4 x 128
  proj_kernel<<<pg, 256, 0, stream>>>(qx, Wq_b, bq, Qb);
  proj_kernel<<<pg, 256, 0, stream>>>(kx, Wk_b, bk, Kb);
  proj_kernel<<<pg, 256, 0, stream>>>(vx, Wv_b, bv, Vb);

  transpose_kernel<<<dim3(S_LEN/64, DMODEL/64, NBATCH), 256, 0, stream>>>(Vb, Vtb);
  vpart_kernel<<<dim3(NTILE, NBATCH), 256, 0, stream>>>(Vb, part);
  suffix_kernel<<<NBATCH, DMODEL, 0, stream>>>(part, sufx);

  score_kernel<<<dim3(NPAIR, NBATCH), 256, 0, stream>>>(Qb, Kb, Pbuf);
  pv_kernel<<<dim3(DMODEL/128, NTILE, NBATCH), 256, 0, stream>>>(Pbuf, Vtb, sufx, out);
}